// Round 7
// baseline (275.923 us; speedup 1.0000x reference)
//
#include <hip/hip_runtime.h>
#include <hip/hip_fp16.h>
#include <math.h>

#define Bn 256
#define Cn 3
#define Hn 224
#define Wn 224
#define CROPD 190

static constexpr int PLANE = Hn * Wn;   // 50176

#define TILE 32
// F (source) tile: fp16 storage
#define FH 72
#define FSTR 76                 // halfs; row stride 152 B
#define F_BYTES (FH * FSTR * 2) // 10944
// P tile: f32
#define PHR 44
#define PSTR 48                 // floats; row stride 192 B
#define P_BYTES (PHR * PSTR * 4) // 8448
// R/T tiles: f32, overlay F region
#define RSTR 40

#define NWG (768 * 49)     // 37,632
#define CHUNK (NWG / 8)

__device__ int    g_i0[Wn];
__device__ float4 g_wt[Wn];

__device__ __forceinline__ float keys_cubic(float x) {
    if (x < 1.f) return ((1.5f * x - 2.5f) * x) * x + 1.f;
    if (x < 2.f) return ((-0.5f * x + 2.5f) * x - 4.f) * x + 2.f;
    return 0.f;
}
__device__ __forceinline__ float rflf(float v) {
    return __int_as_float(__builtin_amdgcn_readfirstlane(__float_as_int(v)));
}
__device__ __forceinline__ int rfli(int v) { return __builtin_amdgcn_readfirstlane(v); }
__device__ __forceinline__ int swz_block(int bid) {
    return (bid & 7) * CHUNK + (bid >> 3);
}

// params[b*12 + {0..7: homography, 8: cos, 9: sin, 10: brightness, 11: flip}]
__global__ void params_kernel(const int* __restrict__ ep_raw,
                              const int* __restrict__ angles,
                              const float* __restrict__ brightness,
                              const int* __restrict__ flip_mask,
                              float* __restrict__ params) {
    int b = threadIdx.x;

    if (b < Wn) {
        float sf = ((float)b + 0.5f) * ((float)CROPD / (float)Wn) - 0.5f;
        int i0 = (int)floorf(sf);
        float w[4]; float s = 0.f;
#pragma unroll
        for (int k = 0; k < 4; k++) {
            int idx = i0 - 1 + k;
            float wk = (idx >= 0 && idx < CROPD) ? keys_cubic(fabsf(sf - (float)idx)) : 0.f;
            w[k] = wk; s += wk;
        }
        float inv = 1.f / s;
        g_i0[b] = i0;
        g_wt[b] = make_float4(w[0] * inv, w[1] * inv, w[2] * inv, w[3] * inv);
    }

    if (b >= Bn) return;

    const double offx[4] = {0.0, 195.0, 195.0, 0.0};
    const double offy[4] = {0.0, 0.0, 195.0, 195.0};
    const double sxc[4]  = {0.0, 223.0, 223.0, 0.0};
    const double syc[4]  = {0.0, 0.0, 223.0, 223.0};
    double M[8][9];
    for (int i = 0; i < 4; i++) {
        double ex = (double)ep_raw[b * 8 + i * 2 + 0] + offx[i];
        double ey = (double)ep_raw[b * 8 + i * 2 + 1] + offy[i];
        double sx = sxc[i], sy = syc[i];
        M[i][0] = ex; M[i][1] = ey; M[i][2] = 1.0;
        M[i][3] = 0.0; M[i][4] = 0.0; M[i][5] = 0.0;
        M[i][6] = -sx * ex; M[i][7] = -sx * ey; M[i][8] = sx;
        M[i + 4][0] = 0.0; M[i + 4][1] = 0.0; M[i + 4][2] = 0.0;
        M[i + 4][3] = ex; M[i + 4][4] = ey; M[i + 4][5] = 1.0;
        M[i + 4][6] = -sy * ex; M[i + 4][7] = -sy * ey; M[i + 4][8] = sy;
    }
    for (int k = 0; k < 8; k++) {
        int piv = k; double best = fabs(M[k][k]);
        for (int r = k + 1; r < 8; r++) {
            double v = fabs(M[r][k]);
            if (v > best) { best = v; piv = r; }
        }
        if (piv != k)
            for (int j = 0; j < 9; j++) { double tt = M[k][j]; M[k][j] = M[piv][j]; M[piv][j] = tt; }
        double inv = 1.0 / M[k][k];
        for (int r = k + 1; r < 8; r++) {
            double f = M[r][k] * inv;
            M[r][k] = 0.0;
            for (int j = k + 1; j < 9; j++) M[r][j] -= f * M[k][j];
        }
    }
    double sol[8];
    for (int k = 7; k >= 0; k--) {
        double s = M[k][8];
        for (int j = k + 1; j < 8; j++) s -= M[k][j] * sol[j];
        sol[k] = s / M[k][k];
    }
    float* p = params + b * 12;
    for (int j = 0; j < 8; j++) p[j] = (float)sol[j];
    double th = ((double)angles[b] - 16.0) * (M_PI / 180.0);
    p[8]  = (float)cos(th);
    p[9]  = (float)sin(th);
    p[10] = 0.85f + 0.3f * brightness[b];
    p[11] = (flip_mask[b] > 0) ? 1.0f : 0.0f;
}

// Per-(batch,tile): rmeta = P-rect (rot bbox) + rot-interior; smeta = source
// bbox of that P-rect under the perspective map + persp-interior.
__global__ void meta_kernel(const float* __restrict__ params,
                            const int* __restrict__ crop_ij,
                            int4* __restrict__ rmeta,
                            int4* __restrict__ smeta) {
    int bt = blockIdx.x * 256 + threadIdx.x;    // < 12544
    int b = bt / 49, t = bt % 49;
    int ty = (t / 7) * TILE, tx = (t % 7) * TILE;
    const float* prm = params + b * 12;

    int x0p, y0p, bwp, bhp;
    {
        float cs = prm[8], sn = prm[9];
        int ci = crop_ij[b * 2 + 0], cj = crop_ij[b * 2 + 1];
        int iymin = max(g_i0[ty] - 1, 0);
        int iymax = min(g_i0[ty + 31] + 2, CROPD - 1);
        int jmin = max(g_i0[tx] - 1, 0);
        int jmax = min(g_i0[tx + 31] + 2, CROPD - 1);
        int ry0 = iymin + ci, ry1 = iymax + ci;
        int rx0 = jmin + cj, rx1 = jmax + cj;
        const float cxc = (Wn - 1) * 0.5f;
        float minrx = 1e30f, maxrx = -1e30f, minry = 1e30f, maxry = -1e30f;
#pragma unroll
        for (int cy = 0; cy < 2; cy++) {
#pragma unroll
            for (int cxr = 0; cxr < 2; cxr++) {
                float dx = (float)(cxr ? rx1 : rx0) - cxc;
                float dy = (float)(cy ? ry1 : ry0) - cxc;
                float rx = cs * dx + sn * dy + cxc;
                float ry = -sn * dx + cs * dy + cxc;
                minrx = fminf(minrx, rx); maxrx = fmaxf(maxrx, rx);
                minry = fminf(minry, ry); maxry = fmaxf(maxry, ry);
            }
        }
        int x0b = min(max((int)floorf(minrx) - 1, 0), Wn - 1);
        int x1b = min(max((int)floorf(maxrx) + 2, 0), Wn - 1);
        int y0b = min(max((int)floorf(minry) - 1, 0), Hn - 1);
        int y1b = min(max((int)floorf(maxry) + 2, 0), Hn - 1);
        x0p = x0b; y0p = y0b;
        bwp = x1b - x0b + 1; bhp = y1b - y0b + 1;
        int inter = (minrx >= 0.5f && maxrx <= 222.0f &&
                     minry >= 0.5f && maxry <= 222.0f) ? 1 : 0;
        rmeta[bt] = make_int4(x0b, y0b, bwp | (inter << 16), bhp);
    }

    {
        float a0 = prm[0], a1 = prm[1], a2 = prm[2];
        float a3 = prm[3], a4 = prm[4], a5 = prm[5];
        float g = prm[6], h = prm[7];
        int x1p = x0p + bwp - 1, y1p = y0p + bhp - 1;
        float minsx = 1e30f, maxsx = -1e30f, minsy = 1e30f, maxsy = -1e30f;
#pragma unroll
        for (int cy = 0; cy < 2; cy++) {
#pragma unroll
            for (int cxr = 0; cxr < 2; cxr++) {
                float Xg = (float)(cxr ? x1p : x0p) + 0.5f;
                float Yg = (float)(cy ? y1p : y0p) + 0.5f;
                float rden = 1.0f / (g * Xg + h * Yg + 1.0f);
                float sx = (a0 * Xg + a1 * Yg + a2) * rden - 0.5f;
                float sy = (a3 * Xg + a4 * Yg + a5) * rden - 0.5f;
                minsx = fminf(minsx, sx); maxsx = fmaxf(maxsx, sx);
                minsy = fminf(minsy, sy); maxsy = fmaxf(maxsy, sy);
            }
        }
        int x0s = min(max((int)floorf(minsx) - 1, 0), Wn - 1);
        int x1s = min(max((int)floorf(maxsx) + 2, 0), Wn - 1);
        int y0s = min(max((int)floorf(minsy) - 1, 0), Hn - 1);
        int y1s = min(max((int)floorf(maxsy) + 2, 0), Hn - 1);
        x0s &= ~3;
        int bws = x1s - x0s + 1, bhs = y1s - y0s + 1;
        int inter = (minsx >= 0.5f && maxsx <= 222.0f &&
                     minsy >= 0.5f && maxsy <= 222.0f) ? 1 : 0;
        smeta[bt] = make_int4(x0s, y0s, bws | (inter << 16), bhs);
    }
}

// On-demand perspective sample with global taps (ultra-rare fallback path).
__device__ __forceinline__ float persp_at(const float* __restrict__ xb,
                                          const float* __restrict__ nb,
                                          bool flip, float bf,
                                          float a0, float a1, float a2,
                                          float a3, float a4, float a5,
                                          float g, float h, int ixp, int iyp) {
    float Xg = (float)ixp + 0.5f, Yg = (float)iyp + 0.5f;
    float rden = __builtin_amdgcn_rcpf(g * Xg + h * Yg + 1.0f);
    float sx = (a0 * Xg + a1 * Yg + a2) * rden - 0.5f;
    float sy = (a3 * Xg + a4 * Yg + a5) * rden - 0.5f;
    float fx0 = floorf(sx), fy0 = floorf(sy);
    float wx = sx - fx0, wy = sy - fy0;
    int x0 = (int)fx0, y0 = (int)fy0;
    float acc = 0.f;
#pragma unroll
    for (int dy = 0; dy < 2; dy++) {
        int yy = y0 + dy;
        float wyv = dy ? wy : 1.f - wy;
        bool yv = (unsigned)yy < (unsigned)Hn;
        int yc = min(max(yy, 0), Hn - 1);
#pragma unroll
        for (int dx = 0; dx < 2; dx++) {
            int xx = x0 + dx;
            float wxv = dx ? wx : 1.f - wx;
            bool v = yv && ((unsigned)xx < (unsigned)Wn);
            int xc = min(max(xx, 0), Wn - 1);
            float wgt = v ? wxv * wyv : 0.f;
            int xs = flip ? (Wn - 1 - xc) : xc;
            acc += (xb[yc * Wn + xs] + 0.625f * nb[yc * Wn + xc]) * bf * wgt;
        }
    }
    return acc;
}

// Fully fused pipeline; F staged as fp16 (storage only), P as f32.
// LDS: F 10,944 B | P 8,448 B; R/T (2x5,120 B) overlay dead F. Total 19,392 B
// -> 8 blocks/CU (100% occupancy; VGPR capped via launch_bounds).
__global__ __launch_bounds__(256, 8) void mega_kernel(const float* __restrict__ xin,
                                                      const float* __restrict__ noise,
                                                      const float* __restrict__ params,
                                                      const int* __restrict__ crop_ij,
                                                      const int4* __restrict__ rmeta,
                                                      const int4* __restrict__ smeta,
                                                      float* __restrict__ out) {
    __shared__ __align__(16) unsigned char smem[F_BYTES + P_BYTES];
    __half* Flds = reinterpret_cast<__half*>(smem);
    float*  Plds = reinterpret_cast<float*>(smem + F_BYTES);
    float*  Rlds = reinterpret_cast<float*>(smem);               // overlays F
    float*  Tlds = reinterpret_cast<float*>(smem + 32 * RSTR * 4);

    int bi = swz_block(blockIdx.x);
    int p = bi / 49;
    int t = bi % 49;
    int ty = (t / 7) * TILE;
    int tx = (t % 7) * TILE;
    int b = p / Cn;
    int tid = threadIdx.x;

    int4 rm = rmeta[b * 49 + t];
    int x0p = rm.x, y0p = rm.y;
    int bwp = rm.z & 0xffff;
    bool interior_r = (rm.z >> 16) != 0;
    int bhp = rm.w;
    int4 sm = smeta[b * 49 + t];
    int x0s = sm.x, y0s = sm.y;
    int bws = sm.z & 0xffff;
    bool interior_s = (sm.z >> 16) != 0;
    int bhs = sm.w;
    int y1s = y0s + bhs - 1;
    bool fitF = (bws <= FH) && (bhs <= FH);
    bool fitP = (bwp <= PHR) && (bhp <= PHR);     // provably true (<=43), kept for safety
    bool fast = fitF && fitP;

    const float* prm = params + b * 12;
    float a0 = rflf(prm[0]), a1 = rflf(prm[1]), a2 = rflf(prm[2]);
    float a3 = rflf(prm[3]), a4 = rflf(prm[4]), a5 = rflf(prm[5]);
    float g = rflf(prm[6]), h = rflf(prm[7]), bf = rflf(prm[10]);
    float cs = rflf(prm[8]), sn = rflf(prm[9]);
    bool flip = rflf(prm[11]) > 0.5f;
    int ci = rfli(crop_ij[b * 2 + 0]);
    int cj = rfli(crop_ij[b * 2 + 1]);

    int iymin = max(g_i0[ty] - 1, 0);
    int nTy = min(g_i0[ty + 31] + 2, CROPD - 1) - iymin + 1;
    int jmin = max(g_i0[tx] - 1, 0);
    int nRx = min(g_i0[tx + 31] + 2, CROPD - 1) - jmin + 1;
    int rx0 = jmin + cj, ry0 = iymin + ci;
    const float cxc = (Wn - 1) * 0.5f;

    const size_t base = (size_t)p * PLANE;
    const float* xb = xin + base;
    const float* nb = noise + base;

    // ---- Phase F: stage (flip(x)+0.625*noise)*bf as fp16 ----
    if (fast) {
        int bwq = (bws + 3) >> 2;               // <= 18
        int sh = (bwq <= 8) ? 3 : ((bwq <= 16) ? 4 : 5);
        int c4 = tid & ((1 << sh) - 1);
        int r0 = tid >> sh;
        int rstep = 256 >> sh;
        bool cok = c4 < bwq;
        for (int yy = y0s + r0; yy <= y1s; yy += rstep) {
            if (cok) {
                int xl = min(x0s + c4 * 4, Wn - 4);
                float4 nv = *reinterpret_cast<const float4*>(&nb[yy * Wn + xl]);
                float4 xv;
                if (flip) {
                    float4 xr = *reinterpret_cast<const float4*>(&xb[yy * Wn + (Wn - 4 - xl)]);
                    xv = make_float4(xr.w, xr.z, xr.y, xr.x);
                } else {
                    xv = *reinterpret_cast<const float4*>(&xb[yy * Wn + xl]);
                }
                unsigned h0 = __half_as_ushort(__float2half((xv.x + 0.625f * nv.x) * bf));
                unsigned h1 = __half_as_ushort(__float2half((xv.y + 0.625f * nv.y) * bf));
                unsigned h2 = __half_as_ushort(__float2half((xv.z + 0.625f * nv.z) * bf));
                unsigned h3 = __half_as_ushort(__float2half((xv.w + 0.625f * nv.w) * bf));
                uint2 u = make_uint2(h0 | (h1 << 16), h2 | (h3 << 16));
                *reinterpret_cast<uint2*>(&Flds[(yy - y0s) * FSTR + (xl - x0s)]) = u;
            }
        }
    }
    __syncthreads();

    // ---- Phase P: perspective bilinear (F taps) -> Plds f32 ----
    if (fast) {
        int bwpq = (bwp + 3) >> 2;              // <= 11
        int c4 = tid & 15;
        int r0 = tid >> 4;
        bool cok = c4 < bwpq;
        int x1p = x0p + bwp - 1;
        if (interior_s) {
            for (int pr = r0; pr < bhp; pr += 16) {
                if (!cok) continue;
                float Yg = (float)(y0p + pr) + 0.5f;
                float pv[4];
#pragma unroll
                for (int j = 0; j < 4; j++) {
                    int px = min(x0p + c4 * 4 + j, x1p);
                    float Xg = (float)px + 0.5f;
                    float rden = __builtin_amdgcn_rcpf(g * Xg + h * Yg + 1.0f);
                    float sx = (a0 * Xg + a1 * Yg + a2) * rden - 0.5f;
                    float sy = (a3 * Xg + a4 * Yg + a5) * rden - 0.5f;
                    float fx0 = floorf(sx), fy0 = floorf(sy);
                    float wx = sx - fx0, wy = sy - fy0;
                    const __half* q = &Flds[((int)fy0 - y0s) * FSTR + ((int)fx0 - x0s)];
                    float q00 = __half2float(q[0]),    q01 = __half2float(q[1]);
                    float q10 = __half2float(q[FSTR]), q11 = __half2float(q[FSTR + 1]);
                    float top = q00 + wx * (q01 - q00);
                    float bot = q10 + wx * (q11 - q10);
                    pv[j] = top + wy * (bot - top);
                }
                *reinterpret_cast<float4*>(&Plds[pr * PSTR + c4 * 4]) =
                    make_float4(pv[0], pv[1], pv[2], pv[3]);
            }
        } else {
            for (int pr = r0; pr < bhp; pr += 16) {
                if (!cok) continue;
                float Yg = (float)(y0p + pr) + 0.5f;
                float pv[4];
#pragma unroll
                for (int j = 0; j < 4; j++) {
                    int px = min(x0p + c4 * 4 + j, x1p);
                    float Xg = (float)px + 0.5f;
                    float rden = __builtin_amdgcn_rcpf(g * Xg + h * Yg + 1.0f);
                    float sx = (a0 * Xg + a1 * Yg + a2) * rden - 0.5f;
                    float sy = (a3 * Xg + a4 * Yg + a5) * rden - 0.5f;
                    float fx0 = floorf(sx), fy0 = floorf(sy);
                    float wx = sx - fx0, wy = sy - fy0;
                    int x0 = (int)fx0, y0 = (int)fy0;
                    float acc = 0.f;
#pragma unroll
                    for (int dy = 0; dy < 2; dy++) {
                        int yy = y0 + dy;
                        float wyv = dy ? wy : 1.f - wy;
                        bool yv = (unsigned)yy < (unsigned)Hn;
                        int yc = min(max(yy, 0), Hn - 1);
#pragma unroll
                        for (int dx = 0; dx < 2; dx++) {
                            int xx = x0 + dx;
                            float wxv = dx ? wx : 1.f - wx;
                            bool v = yv && ((unsigned)xx < (unsigned)Wn);
                            int xc = min(max(xx, 0), Wn - 1);
                            float wgt = v ? wxv * wyv : 0.f;
                            acc += __half2float(Flds[(yc - y0s) * FSTR + (xc - x0s)]) * wgt;
                        }
                    }
                    pv[j] = acc;
                }
                *reinterpret_cast<float4*>(&Plds[pr * PSTR + c4 * 4]) =
                    make_float4(pv[0], pv[1], pv[2], pv[3]);
            }
        }
    }
    __syncthreads();

    // ---- Phase R: rotation bilinear (P taps) -> Rlds ----
    {
        int rc = tid & 31;
        int rbase = tid >> 5;
        bool cok = rc < nRx;
        float dxc = (float)(rx0 + rc) - cxc;
        float bx = cs * dxc + cxc;
        float by = -sn * dxc + cxc;
        if (fast && interior_r) {
#pragma unroll
            for (int it = 0; it < 4; it++) {
                int rr = it * 8 + rbase;
                if (rr < nTy && cok) {
                    float dyr = (float)(ry0 + rr) - cxc;
                    float srx = bx + sn * dyr;
                    float sry = by + cs * dyr;
                    float fx0 = floorf(srx), fy0 = floorf(sry);
                    float wx = srx - fx0, wy = sry - fy0;
                    const float* q = &Plds[((int)fy0 - y0p) * PSTR + ((int)fx0 - x0p)];
                    float top = q[0] + wx * (q[1] - q[0]);
                    float bot = q[PSTR] + wx * (q[PSTR + 1] - q[PSTR]);
                    Rlds[rr * RSTR + rc] = top + wy * (bot - top);
                }
            }
        } else if (fast) {
#pragma unroll
            for (int it = 0; it < 4; it++) {
                int rr = it * 8 + rbase;
                if (rr < nTy && cok) {
                    float dyr = (float)(ry0 + rr) - cxc;
                    float srx = bx + sn * dyr;
                    float sry = by + cs * dyr;
                    float fx0 = floorf(srx), fy0 = floorf(sry);
                    float wx = srx - fx0, wy = sry - fy0;
                    int x0 = (int)fx0, y0 = (int)fy0;
                    float acc = 0.f;
#pragma unroll
                    for (int ddy = 0; ddy < 2; ddy++) {
                        int yy = y0 + ddy;
                        float wyv = ddy ? wy : 1.f - wy;
                        bool yv = (unsigned)yy < (unsigned)Hn;
                        int yc = min(max(yy, 0), Hn - 1);
#pragma unroll
                        for (int ddx = 0; ddx < 2; ddx++) {
                            int xx = x0 + ddx;
                            float wxv = ddx ? wx : 1.f - wx;
                            bool v = yv && ((unsigned)xx < (unsigned)Wn);
                            int xc = min(max(xx, 0), Wn - 1);
                            float wgt = v ? wxv * wyv : 0.f;
                            acc += Plds[(yc - y0p) * PSTR + (xc - x0p)] * wgt;
                        }
                    }
                    Rlds[rr * RSTR + rc] = acc;
                }
            }
        } else {
#pragma unroll
            for (int it = 0; it < 4; it++) {
                int rr = it * 8 + rbase;
                if (rr < nTy && cok) {
                    float dyr = (float)(ry0 + rr) - cxc;
                    float srx = bx + sn * dyr;
                    float sry = by + cs * dyr;
                    float fx0 = floorf(srx), fy0 = floorf(sry);
                    float wx = srx - fx0, wy = sry - fy0;
                    int x0 = (int)fx0, y0 = (int)fy0;
                    float acc = 0.f;
#pragma unroll
                    for (int ddy = 0; ddy < 2; ddy++) {
                        int yy = y0 + ddy;
                        float wyv = ddy ? wy : 1.f - wy;
                        bool yv = (unsigned)yy < (unsigned)Hn;
                        int yc = min(max(yy, 0), Hn - 1);
#pragma unroll
                        for (int ddx = 0; ddx < 2; ddx++) {
                            int xx = x0 + ddx;
                            float wxv = ddx ? wx : 1.f - wx;
                            bool v = yv && ((unsigned)xx < (unsigned)Wn);
                            int xc = min(max(xx, 0), Wn - 1);
                            float wgt = v ? wxv * wyv : 0.f;
                            if (wgt != 0.f)
                                acc += persp_at(xb, nb, flip, bf, a0, a1, a2,
                                                a3, a4, a5, g, h, xc, yc) * wgt;
                        }
                    }
                    Rlds[rr * RSTR + rc] = acc;
                }
            }
        }
    }
    __syncthreads();

    // ---- Phase T: horizontal bicubic ----
    {
        int oc = tid & 31;
        int rbase = tid >> 5;
        int ox = tx + oc;
        float4 w = g_wt[ox];
        int j0 = g_i0[ox];
        int jc0 = min(max(j0 - 1, 0), CROPD - 1) - jmin;
        int jc1 = min(max(j0 + 0, 0), CROPD - 1) - jmin;
        int jc2 = min(max(j0 + 1, 0), CROPD - 1) - jmin;
        int jc3 = min(max(j0 + 2, 0), CROPD - 1) - jmin;
#pragma unroll
        for (int it = 0; it < 4; it++) {
            int rr = it * 8 + rbase;
            if (rr < nTy) {
                const float* row = &Rlds[rr * RSTR];
                Tlds[rr * RSTR + oc] = w.x * row[jc0] + w.y * row[jc1] +
                                       w.z * row[jc2] + w.w * row[jc3];
            }
        }
    }
    __syncthreads();

    // ---- Phase V: vertical bicubic, float4 store ----
    {
        int r = tid >> 3, cg = tid & 7;
        int oy = ty + r, ox0 = tx + cg * 4;
        float4 w = g_wt[oy];
        int i0y = g_i0[oy];
        float wk[4] = {w.x, w.y, w.z, w.w};
        float4 acc = make_float4(0.f, 0.f, 0.f, 0.f);
#pragma unroll
        for (int k = 0; k < 4; k++) {
            int iyc = min(max(i0y - 1 + k, 0), CROPD - 1) - iymin;
            float4 v = *reinterpret_cast<const float4*>(&Tlds[iyc * RSTR + cg * 4]);
            acc.x += wk[k] * v.x;
            acc.y += wk[k] * v.y;
            acc.z += wk[k] * v.z;
            acc.w += wk[k] * v.w;
        }
        *reinterpret_cast<float4*>(out + base + (size_t)oy * Wn + ox0) = acc;
    }
}

extern "C" void kernel_launch(void* const* d_in, const int* in_sizes, int n_in,
                              void* d_out, int out_size, void* d_ws, size_t ws_size,
                              hipStream_t stream) {
    const float* x          = (const float*)d_in[0];
    const float* noise      = (const float*)d_in[1];
    const float* brightness = (const float*)d_in[2];
    const int*   flip_mask  = (const int*)d_in[3];
    const int*   ep_raw     = (const int*)d_in[4];
    const int*   angles     = (const int*)d_in[5];
    const int*   crop_ij    = (const int*)d_in[6];
    float* out = (float*)d_out;

    float* params = (float*)d_ws;                              // 12 KB
    int4*  rmeta  = (int4*)((char*)d_ws + 16384);              // 12544*16
    int4*  smeta  = (int4*)((char*)d_ws + 16384 + 200704);

    params_kernel<<<1, 256, 0, stream>>>(ep_raw, angles, brightness, flip_mask, params);
    meta_kernel<<<49, 256, 0, stream>>>(params, crop_ij, rmeta, smeta);
    mega_kernel<<<NWG, 256, 0, stream>>>(x, noise, params, crop_ij, rmeta, smeta, out);
}

// Round 8
// 249.539 us; speedup vs baseline: 1.1057x; 1.1057x over previous
//
#include <hip/hip_runtime.h>
#include <math.h>

#define Bn 256
#define Cn 3
#define Hn 224
#define Wn 224
#define CROPD 190

static constexpr int PLANE = Hn * Wn;   // 50176

#define TILE 32
// F (source) tile: f32
#define FH 72
#define FSTR 76                  // floats
// P tile: f32
#define PHR 44
#define PSTR 48
// R/T tiles overlay F region
#define RSTR 40

#define NWG (768 * 49)     // 37,632
#define CHUNK (NWG / 8)

__device__ int    g_i0[Wn];
__device__ float4 g_wt[Wn];

__device__ __forceinline__ float keys_cubic(float x) {
    if (x < 1.f) return ((1.5f * x - 2.5f) * x) * x + 1.f;
    if (x < 2.f) return ((-0.5f * x + 2.5f) * x - 4.f) * x + 2.f;
    return 0.f;
}
__device__ __forceinline__ float rflf(float v) {
    return __int_as_float(__builtin_amdgcn_readfirstlane(__float_as_int(v)));
}
__device__ __forceinline__ int rfli(int v) { return __builtin_amdgcn_readfirstlane(v); }
__device__ __forceinline__ int swz_block(int bid) {
    return (bid & 7) * CHUNK + (bid >> 3);
}

// params[b*12 + {0..7: homography, 8: cos, 9: sin, 10: brightness, 11: flip}]
__global__ void params_kernel(const int* __restrict__ ep_raw,
                              const int* __restrict__ angles,
                              const float* __restrict__ brightness,
                              const int* __restrict__ flip_mask,
                              float* __restrict__ params) {
    int b = threadIdx.x;

    if (b < Wn) {
        float sf = ((float)b + 0.5f) * ((float)CROPD / (float)Wn) - 0.5f;
        int i0 = (int)floorf(sf);
        float w[4]; float s = 0.f;
#pragma unroll
        for (int k = 0; k < 4; k++) {
            int idx = i0 - 1 + k;
            float wk = (idx >= 0 && idx < CROPD) ? keys_cubic(fabsf(sf - (float)idx)) : 0.f;
            w[k] = wk; s += wk;
        }
        float inv = 1.f / s;
        g_i0[b] = i0;
        g_wt[b] = make_float4(w[0] * inv, w[1] * inv, w[2] * inv, w[3] * inv);
    }

    if (b >= Bn) return;

    const double offx[4] = {0.0, 195.0, 195.0, 0.0};
    const double offy[4] = {0.0, 0.0, 195.0, 195.0};
    const double sxc[4]  = {0.0, 223.0, 223.0, 0.0};
    const double syc[4]  = {0.0, 0.0, 223.0, 223.0};
    double M[8][9];
    for (int i = 0; i < 4; i++) {
        double ex = (double)ep_raw[b * 8 + i * 2 + 0] + offx[i];
        double ey = (double)ep_raw[b * 8 + i * 2 + 1] + offy[i];
        double sx = sxc[i], sy = syc[i];
        M[i][0] = ex; M[i][1] = ey; M[i][2] = 1.0;
        M[i][3] = 0.0; M[i][4] = 0.0; M[i][5] = 0.0;
        M[i][6] = -sx * ex; M[i][7] = -sx * ey; M[i][8] = sx;
        M[i + 4][0] = 0.0; M[i + 4][1] = 0.0; M[i + 4][2] = 0.0;
        M[i + 4][3] = ex; M[i + 4][4] = ey; M[i + 4][5] = 1.0;
        M[i + 4][6] = -sy * ex; M[i + 4][7] = -sy * ey; M[i + 4][8] = sy;
    }
    for (int k = 0; k < 8; k++) {
        int piv = k; double best = fabs(M[k][k]);
        for (int r = k + 1; r < 8; r++) {
            double v = fabs(M[r][k]);
            if (v > best) { best = v; piv = r; }
        }
        if (piv != k)
            for (int j = 0; j < 9; j++) { double tt = M[k][j]; M[k][j] = M[piv][j]; M[piv][j] = tt; }
        double inv = 1.0 / M[k][k];
        for (int r = k + 1; r < 8; r++) {
            double f = M[r][k] * inv;
            M[r][k] = 0.0;
            for (int j = k + 1; j < 9; j++) M[r][j] -= f * M[k][j];
        }
    }
    double sol[8];
    for (int k = 7; k >= 0; k--) {
        double s = M[k][8];
        for (int j = k + 1; j < 8; j++) s -= M[k][j] * sol[j];
        sol[k] = s / M[k][k];
    }
    float* p = params + b * 12;
    for (int j = 0; j < 8; j++) p[j] = (float)sol[j];
    double th = ((double)angles[b] - 16.0) * (M_PI / 180.0);
    p[8]  = (float)cos(th);
    p[9]  = (float)sin(th);
    p[10] = 0.85f + 0.3f * brightness[b];
    p[11] = (flip_mask[b] > 0) ? 1.0f : 0.0f;
}

// Per-(batch,tile): rmeta = P-rect (rot bbox) + rot-interior; smeta = source
// bbox of that P-rect under the perspective map + persp-interior.
__global__ void meta_kernel(const float* __restrict__ params,
                            const int* __restrict__ crop_ij,
                            int4* __restrict__ rmeta,
                            int4* __restrict__ smeta) {
    int bt = blockIdx.x * 256 + threadIdx.x;    // < 12544
    int b = bt / 49, t = bt % 49;
    int ty = (t / 7) * TILE, tx = (t % 7) * TILE;
    const float* prm = params + b * 12;

    int x0p, y0p, bwp, bhp;
    {
        float cs = prm[8], sn = prm[9];
        int ci = crop_ij[b * 2 + 0], cj = crop_ij[b * 2 + 1];
        int iymin = max(g_i0[ty] - 1, 0);
        int iymax = min(g_i0[ty + 31] + 2, CROPD - 1);
        int jmin = max(g_i0[tx] - 1, 0);
        int jmax = min(g_i0[tx + 31] + 2, CROPD - 1);
        int ry0 = iymin + ci, ry1 = iymax + ci;
        int rx0 = jmin + cj, rx1 = jmax + cj;
        const float cxc = (Wn - 1) * 0.5f;
        float minrx = 1e30f, maxrx = -1e30f, minry = 1e30f, maxry = -1e30f;
#pragma unroll
        for (int cy = 0; cy < 2; cy++) {
#pragma unroll
            for (int cxr = 0; cxr < 2; cxr++) {
                float dx = (float)(cxr ? rx1 : rx0) - cxc;
                float dy = (float)(cy ? ry1 : ry0) - cxc;
                float rx = cs * dx + sn * dy + cxc;
                float ry = -sn * dx + cs * dy + cxc;
                minrx = fminf(minrx, rx); maxrx = fmaxf(maxrx, rx);
                minry = fminf(minry, ry); maxry = fmaxf(maxry, ry);
            }
        }
        int x0b = min(max((int)floorf(minrx) - 1, 0), Wn - 1);
        int x1b = min(max((int)floorf(maxrx) + 2, 0), Wn - 1);
        int y0b = min(max((int)floorf(minry) - 1, 0), Hn - 1);
        int y1b = min(max((int)floorf(maxry) + 2, 0), Hn - 1);
        x0p = x0b; y0p = y0b;
        bwp = x1b - x0b + 1; bhp = y1b - y0b + 1;
        int inter = (minrx >= 0.5f && maxrx <= 222.0f &&
                     minry >= 0.5f && maxry <= 222.0f) ? 1 : 0;
        rmeta[bt] = make_int4(x0b, y0b, bwp | (inter << 16), bhp);
    }

    {
        float a0 = prm[0], a1 = prm[1], a2 = prm[2];
        float a3 = prm[3], a4 = prm[4], a5 = prm[5];
        float g = prm[6], h = prm[7];
        int x1p = x0p + bwp - 1, y1p = y0p + bhp - 1;
        float minsx = 1e30f, maxsx = -1e30f, minsy = 1e30f, maxsy = -1e30f;
#pragma unroll
        for (int cy = 0; cy < 2; cy++) {
#pragma unroll
            for (int cxr = 0; cxr < 2; cxr++) {
                float Xg = (float)(cxr ? x1p : x0p) + 0.5f;
                float Yg = (float)(cy ? y1p : y0p) + 0.5f;
                float rden = 1.0f / (g * Xg + h * Yg + 1.0f);
                float sx = (a0 * Xg + a1 * Yg + a2) * rden - 0.5f;
                float sy = (a3 * Xg + a4 * Yg + a5) * rden - 0.5f;
                minsx = fminf(minsx, sx); maxsx = fmaxf(maxsx, sx);
                minsy = fminf(minsy, sy); maxsy = fmaxf(maxsy, sy);
            }
        }
        int x0s = min(max((int)floorf(minsx) - 1, 0), Wn - 1);
        int x1s = min(max((int)floorf(maxsx) + 2, 0), Wn - 1);
        int y0s = min(max((int)floorf(minsy) - 1, 0), Hn - 1);
        int y1s = min(max((int)floorf(maxsy) + 2, 0), Hn - 1);
        x0s &= ~3;
        int bws = x1s - x0s + 1, bhs = y1s - y0s + 1;
        int inter = (minsx >= 0.5f && maxsx <= 222.0f &&
                     minsy >= 0.5f && maxsy <= 222.0f) ? 1 : 0;
        smeta[bt] = make_int4(x0s, y0s, bws | (inter << 16), bhs);
    }
}

// On-demand perspective sample with global taps (ultra-rare fallback path).
__device__ __forceinline__ float persp_at(const float* __restrict__ xb,
                                          const float* __restrict__ nb,
                                          bool flip, float bf,
                                          float a0, float a1, float a2,
                                          float a3, float a4, float a5,
                                          float g, float h, int ixp, int iyp) {
    float Xg = (float)ixp + 0.5f, Yg = (float)iyp + 0.5f;
    float rden = __builtin_amdgcn_rcpf(g * Xg + h * Yg + 1.0f);
    float sx = (a0 * Xg + a1 * Yg + a2) * rden - 0.5f;
    float sy = (a3 * Xg + a4 * Yg + a5) * rden - 0.5f;
    float fx0 = floorf(sx), fy0 = floorf(sy);
    float wx = sx - fx0, wy = sy - fy0;
    int x0 = (int)fx0, y0 = (int)fy0;
    float acc = 0.f;
#pragma unroll
    for (int dy = 0; dy < 2; dy++) {
        int yy = y0 + dy;
        float wyv = dy ? wy : 1.f - wy;
        bool yv = (unsigned)yy < (unsigned)Hn;
        int yc = min(max(yy, 0), Hn - 1);
#pragma unroll
        for (int dx = 0; dx < 2; dx++) {
            int xx = x0 + dx;
            float wxv = dx ? wx : 1.f - wx;
            bool v = yv && ((unsigned)xx < (unsigned)Wn);
            int xc = min(max(xx, 0), Wn - 1);
            float wgt = v ? wxv * wyv : 0.f;
            int xs = flip ? (Wn - 1 - xc) : xc;
            acc += (xb[yc * Wn + xs] + 0.625f * nb[yc * Wn + xc]) * bf * wgt;
        }
    }
    return acc;
}

// Fully fused pipeline. F and P both f32; R/T overlay dead F.
// LDS = 72*76*4 + 44*48*4 = 30,336 B -> 5 blocks/CU.
__global__ __launch_bounds__(256, 5) void mega_kernel(const float* __restrict__ xin,
                                                      const float* __restrict__ noise,
                                                      const float* __restrict__ params,
                                                      const int* __restrict__ crop_ij,
                                                      const int4* __restrict__ rmeta,
                                                      const int4* __restrict__ smeta,
                                                      float* __restrict__ out) {
    __shared__ __align__(16) float smem[FH * FSTR + PHR * PSTR];
    float* Flds = smem;
    float* Plds = smem + FH * FSTR;
    float* Rlds = smem;                      // overlays F (dead after P phase)
    float* Tlds = smem + 32 * RSTR;

    int bi = swz_block(blockIdx.x);
    int p = bi / 49;
    int t = bi % 49;
    int ty = (t / 7) * TILE;
    int tx = (t % 7) * TILE;
    int b = p / Cn;
    int tid = threadIdx.x;

    int4 rm = rmeta[b * 49 + t];
    int x0p = rm.x, y0p = rm.y;
    int bwp = rm.z & 0xffff;
    bool interior_r = (rm.z >> 16) != 0;
    int bhp = rm.w;
    int4 sm = smeta[b * 49 + t];
    int x0s = sm.x, y0s = sm.y;
    int bws = sm.z & 0xffff;
    bool interior_s = (sm.z >> 16) != 0;
    int bhs = sm.w;
    bool fitF = (bws <= FH) && (bhs <= FH);
    bool fitP = (bwp <= PHR) && (bhp <= PHR);
    bool fast = fitF && fitP;

    const float* prm = params + b * 12;
    float a0 = rflf(prm[0]), a1 = rflf(prm[1]), a2 = rflf(prm[2]);
    float a3 = rflf(prm[3]), a4 = rflf(prm[4]), a5 = rflf(prm[5]);
    float g = rflf(prm[6]), h = rflf(prm[7]), bf = rflf(prm[10]);
    float cs = rflf(prm[8]), sn = rflf(prm[9]);
    bool flip = rflf(prm[11]) > 0.5f;
    int ci = rfli(crop_ij[b * 2 + 0]);
    int cj = rfli(crop_ij[b * 2 + 1]);

    int iymin = max(g_i0[ty] - 1, 0);
    int nTy = min(g_i0[ty + 31] + 2, CROPD - 1) - iymin + 1;
    int jmin = max(g_i0[tx] - 1, 0);
    int nRx = min(g_i0[tx + 31] + 2, CROPD - 1) - jmin + 1;
    int rx0 = jmin + cj, ry0 = iymin + ci;
    const float cxc = (Wn - 1) * 0.5f;

    const size_t base = (size_t)p * PLANE;
    const float* xb = xin + base;
    const float* nb = noise + base;

    // ---- Phase F: stage (flip(x)+0.625*noise)*bf, f32, linear magic-div map ----
    if (fast) {
        int bwq = (bws + 3) >> 2;                     // quads/row, <= 18
        unsigned Mf = (1u << 20) / (unsigned)bwq + 1; // uniform, once per block
        int tot = bhs * bwq;                          // <= 1296 (exact magic-div range)
        for (int e = tid; e < tot; e += 256) {
            int fr = (int)(((unsigned)e * Mf) >> 20);
            int fc = e - fr * bwq;
            int yy = y0s + fr;
            int xl = min(x0s + fc * 4, Wn - 4);       // 4-aligned (x0s aligned, 220%4==0)
            float4 nv = *reinterpret_cast<const float4*>(&nb[yy * Wn + xl]);
            float4 xv;
            if (flip) {
                float4 xr = *reinterpret_cast<const float4*>(&xb[yy * Wn + (Wn - 4 - xl)]);
                xv = make_float4(xr.w, xr.z, xr.y, xr.x);
            } else {
                xv = *reinterpret_cast<const float4*>(&xb[yy * Wn + xl]);
            }
            float4 f = make_float4((xv.x + 0.625f * nv.x) * bf,
                                   (xv.y + 0.625f * nv.y) * bf,
                                   (xv.z + 0.625f * nv.z) * bf,
                                   (xv.w + 0.625f * nv.w) * bf);
            *reinterpret_cast<float4*>(&Flds[fr * FSTR + (xl - x0s)]) = f;
        }
    }
    __syncthreads();

    // ---- Phase P: perspective bilinear -> Plds, linear magic-div map ----
    // Padding elems (col quads past bwp) compute garbage from in-LDS reads into
    // never-read P slots — safe by construction (reads only, bounded stores).
    if (fast) {
        int bwpq = (bwp + 3) >> 2;                     // <= 11
        unsigned Mp = (1u << 20) / (unsigned)bwpq + 1;
        int tot = bhp * bwpq;                          // <= 484
        if (interior_s) {
            for (int e = tid; e < tot; e += 256) {
                int pr = (int)(((unsigned)e * Mp) >> 20);
                int pc = e - pr * bwpq;
                float Yg = (float)(y0p + pr) + 0.5f;
                float Xg0 = (float)(x0p + pc * 4) + 0.5f;
                float nx = a0 * Xg0 + (a1 * Yg + a2);
                float ny = a3 * Xg0 + (a4 * Yg + a5);
                float dn = g * Xg0 + (h * Yg + 1.0f);
                float pv[4];
#pragma unroll
                for (int j = 0; j < 4; j++) {
                    float r = __builtin_amdgcn_rcpf(dn);
                    float sx = nx * r - 0.5f;          // > 0 (interior)
                    float sy = ny * r - 0.5f;
                    int ix = (int)sx; float wx = sx - (float)ix;
                    int iy = (int)sy; float wy = sy - (float)iy;
                    const float* q = &Flds[(iy - y0s) * FSTR + (ix - x0s)];
                    float top = q[0] + wx * (q[1] - q[0]);
                    float bot = q[FSTR] + wx * (q[FSTR + 1] - q[FSTR]);
                    pv[j] = top + wy * (bot - top);
                    nx += a0; ny += a3; dn += g;
                }
                *reinterpret_cast<float4*>(&Plds[pr * PSTR + pc * 4]) =
                    make_float4(pv[0], pv[1], pv[2], pv[3]);
            }
        } else {
            for (int e = tid; e < tot; e += 256) {
                int pr = (int)(((unsigned)e * Mp) >> 20);
                int pc = e - pr * bwpq;
                float Yg = (float)(y0p + pr) + 0.5f;
                float Xg0 = (float)(x0p + pc * 4) + 0.5f;
                float nx = a0 * Xg0 + (a1 * Yg + a2);
                float ny = a3 * Xg0 + (a4 * Yg + a5);
                float dn = g * Xg0 + (h * Yg + 1.0f);
                float pv[4];
#pragma unroll
                for (int j = 0; j < 4; j++) {
                    float r = __builtin_amdgcn_rcpf(dn);
                    float sx = nx * r - 0.5f;
                    float sy = ny * r - 0.5f;
                    float fx0 = floorf(sx), fy0 = floorf(sy);
                    float wx = sx - fx0, wy = sy - fy0;
                    int x0 = (int)fx0, y0 = (int)fy0;
                    float acc = 0.f;
#pragma unroll
                    for (int dy = 0; dy < 2; dy++) {
                        int yy = y0 + dy;
                        float wyv = dy ? wy : 1.f - wy;
                        bool yv = (unsigned)yy < (unsigned)Hn;
                        int yc = min(max(yy, 0), Hn - 1);
#pragma unroll
                        for (int dx = 0; dx < 2; dx++) {
                            int xx = x0 + dx;
                            float wxv = dx ? wx : 1.f - wx;
                            bool v = yv && ((unsigned)xx < (unsigned)Wn);
                            int xc = min(max(xx, 0), Wn - 1);
                            float wgt = v ? wxv * wyv : 0.f;
                            acc += Flds[(yc - y0s) * FSTR + (xc - x0s)] * wgt;
                        }
                    }
                    pv[j] = acc;
                    nx += a0; ny += a3; dn += g;
                }
                *reinterpret_cast<float4*>(&Plds[pr * PSTR + pc * 4]) =
                    make_float4(pv[0], pv[1], pv[2], pv[3]);
            }
        }
    }
    __syncthreads();

    // ---- Phase R: rotation bilinear (P taps) -> Rlds ----
    {
        int rc = tid & 31;
        int rbase = tid >> 5;
        bool cok = rc < nRx;
        float dxc = (float)(rx0 + rc) - cxc;
        float bx = cs * dxc + cxc;
        float by = -sn * dxc + cxc;
        if (fast && interior_r) {
#pragma unroll
            for (int it = 0; it < 4; it++) {
                int rr = it * 8 + rbase;
                if (rr < nTy && cok) {
                    float dyr = (float)(ry0 + rr) - cxc;
                    float srx = bx + sn * dyr;         // > 0 (interior)
                    float sry = by + cs * dyr;
                    int ix = (int)srx; float wx = srx - (float)ix;
                    int iy = (int)sry; float wy = sry - (float)iy;
                    const float* q = &Plds[(iy - y0p) * PSTR + (ix - x0p)];
                    float top = q[0] + wx * (q[1] - q[0]);
                    float bot = q[PSTR] + wx * (q[PSTR + 1] - q[PSTR]);
                    Rlds[rr * RSTR + rc] = top + wy * (bot - top);
                }
            }
        } else if (fast) {
#pragma unroll
            for (int it = 0; it < 4; it++) {
                int rr = it * 8 + rbase;
                if (rr < nTy && cok) {
                    float dyr = (float)(ry0 + rr) - cxc;
                    float srx = bx + sn * dyr;
                    float sry = by + cs * dyr;
                    float fx0 = floorf(srx), fy0 = floorf(sry);
                    float wx = srx - fx0, wy = sry - fy0;
                    int x0 = (int)fx0, y0 = (int)fy0;
                    float acc = 0.f;
#pragma unroll
                    for (int ddy = 0; ddy < 2; ddy++) {
                        int yy = y0 + ddy;
                        float wyv = ddy ? wy : 1.f - wy;
                        bool yv = (unsigned)yy < (unsigned)Hn;
                        int yc = min(max(yy, 0), Hn - 1);
#pragma unroll
                        for (int ddx = 0; ddx < 2; ddx++) {
                            int xx = x0 + ddx;
                            float wxv = ddx ? wx : 1.f - wx;
                            bool v = yv && ((unsigned)xx < (unsigned)Wn);
                            int xc = min(max(xx, 0), Wn - 1);
                            float wgt = v ? wxv * wyv : 0.f;
                            acc += Plds[(yc - y0p) * PSTR + (xc - x0p)] * wgt;
                        }
                    }
                    Rlds[rr * RSTR + rc] = acc;
                }
            }
        } else {
#pragma unroll
            for (int it = 0; it < 4; it++) {
                int rr = it * 8 + rbase;
                if (rr < nTy && cok) {
                    float dyr = (float)(ry0 + rr) - cxc;
                    float srx = bx + sn * dyr;
                    float sry = by + cs * dyr;
                    float fx0 = floorf(srx), fy0 = floorf(sry);
                    float wx = srx - fx0, wy = sry - fy0;
                    int x0 = (int)fx0, y0 = (int)fy0;
                    float acc = 0.f;
#pragma unroll
                    for (int ddy = 0; ddy < 2; ddy++) {
                        int yy = y0 + ddy;
                        float wyv = ddy ? wy : 1.f - wy;
                        bool yv = (unsigned)yy < (unsigned)Hn;
                        int yc = min(max(yy, 0), Hn - 1);
#pragma unroll
                        for (int ddx = 0; ddx < 2; ddx++) {
                            int xx = x0 + ddx;
                            float wxv = ddx ? wx : 1.f - wx;
                            bool v = yv && ((unsigned)xx < (unsigned)Wn);
                            int xc = min(max(xx, 0), Wn - 1);
                            float wgt = v ? wxv * wyv : 0.f;
                            if (wgt != 0.f)
                                acc += persp_at(xb, nb, flip, bf, a0, a1, a2,
                                                a3, a4, a5, g, h, xc, yc) * wgt;
                        }
                    }
                    Rlds[rr * RSTR + rc] = acc;
                }
            }
        }
    }
    __syncthreads();

    // ---- Phase T: horizontal bicubic ----
    {
        int oc = tid & 31;
        int rbase = tid >> 5;
        int ox = tx + oc;
        float4 w = g_wt[ox];
        int j0 = g_i0[ox];
        int jc0 = min(max(j0 - 1, 0), CROPD - 1) - jmin;
        int jc1 = min(max(j0 + 0, 0), CROPD - 1) - jmin;
        int jc2 = min(max(j0 + 1, 0), CROPD - 1) - jmin;
        int jc3 = min(max(j0 + 2, 0), CROPD - 1) - jmin;
#pragma unroll
        for (int it = 0; it < 4; it++) {
            int rr = it * 8 + rbase;
            if (rr < nTy) {
                const float* row = &Rlds[rr * RSTR];
                Tlds[rr * RSTR + oc] = w.x * row[jc0] + w.y * row[jc1] +
                                       w.z * row[jc2] + w.w * row[jc3];
            }
        }
    }
    __syncthreads();

    // ---- Phase V: vertical bicubic, float4 store ----
    {
        int r = tid >> 3, cg = tid & 7;
        int oy = ty + r, ox0 = tx + cg * 4;
        float4 w = g_wt[oy];
        int i0y = g_i0[oy];
        float wk[4] = {w.x, w.y, w.z, w.w};
        float4 acc = make_float4(0.f, 0.f, 0.f, 0.f);
#pragma unroll
        for (int k = 0; k < 4; k++) {
            int iyc = min(max(i0y - 1 + k, 0), CROPD - 1) - iymin;
            float4 v = *reinterpret_cast<const float4*>(&Tlds[iyc * RSTR + cg * 4]);
            acc.x += wk[k] * v.x;
            acc.y += wk[k] * v.y;
            acc.z += wk[k] * v.z;
            acc.w += wk[k] * v.w;
        }
        *reinterpret_cast<float4*>(out + base + (size_t)oy * Wn + ox0) = acc;
    }
}

extern "C" void kernel_launch(void* const* d_in, const int* in_sizes, int n_in,
                              void* d_out, int out_size, void* d_ws, size_t ws_size,
                              hipStream_t stream) {
    const float* x          = (const float*)d_in[0];
    const float* noise      = (const float*)d_in[1];
    const float* brightness = (const float*)d_in[2];
    const int*   flip_mask  = (const int*)d_in[3];
    const int*   ep_raw     = (const int*)d_in[4];
    const int*   angles     = (const int*)d_in[5];
    const int*   crop_ij    = (const int*)d_in[6];
    float* out = (float*)d_out;

    float* params = (float*)d_ws;                              // 12 KB
    int4*  rmeta  = (int4*)((char*)d_ws + 16384);              // 12544*16
    int4*  smeta  = (int4*)((char*)d_ws + 16384 + 200704);

    params_kernel<<<1, 256, 0, stream>>>(ep_raw, angles, brightness, flip_mask, params);
    meta_kernel<<<49, 256, 0, stream>>>(params, crop_ij, rmeta, smeta);
    mega_kernel<<<NWG, 256, 0, stream>>>(x, noise, params, crop_ij, rmeta, smeta, out);
}